// Round 3
// baseline (210.943 us; speedup 1.0000x reference)
//
#include <hip/hip_runtime.h>

typedef _Float16 f16;
typedef _Float16 f16x4 __attribute__((ext_vector_type(4)));
typedef _Float16 f16x8 __attribute__((ext_vector_type(8)));
typedef float    f32x4 __attribute__((ext_vector_type(4)));

#define S2C 2.88539008177792681472f   // 2*log2(e)

// ws layout, f16-element offsets (unchanged — prep is identical to previous rounds)
#define OFF_STF  0u          // states A-frags [10][256 rg2][2 rt][2 ks][64 lane][8]  5242880
#define OFF_AC   5242880u    // action f16 compact [8192][10][16]                     1310720
#define OFF_WEF  6553600u    // W_edge B-frags [90][4 ks][8 cg][64 lane][8]           1474560
#define OFF_WNF  8028160u    // W_node B-frags K-permuted [10][7 ks][4 c][64 lane][8]  143360
#define OFF_BE2  8171520u    // f32: be2[11520], bn2[640]; then 8 f16 zeros
#define OFF_Z    8195840u    // 8 f16 zeros (pad source for action kstep)

__device__ __forceinline__ float fast_exp2(float x){
#if __has_builtin(__builtin_amdgcn_exp2f)
    return __builtin_amdgcn_exp2f(x);
#else
    return exp2f(x);
#endif
}
__device__ __forceinline__ float fast_rcp(float x){
#if __has_builtin(__builtin_amdgcn_rcpf)
    return __builtin_amdgcn_rcpf(x);
#else
    return 1.0f/x;
#endif
}

#define MFMA16(a,b,c) __builtin_amdgcn_mfma_f32_16x16x32_f16(a,b,c,0,0,0)

// direct global->LDS DMA, 16 B/lane; LDS dest is wave-uniform base + lane*16
#define GLD16(g, l) __builtin_amdgcn_global_load_lds( \
    (const __attribute__((address_space(1))) void*)(g), \
    (__attribute__((address_space(3))) void*)(l), 16, 0, 0)

// ---------------- prologue: cvt + fragment-order + bias scale (unchanged) ----------------
__global__ void prep(const float* __restrict__ st, const float* __restrict__ ac,
                     const float* __restrict__ We, const float* __restrict__ be,
                     const float* __restrict__ Wn, const float* __restrict__ bn,
                     f16* __restrict__ ws16){
    const int bid = blockIdx.x, t = threadIdx.x;
    if (bid < 2560){                                   // states -> A-fragment order
        int g = bid*256 + t;                           // [node][rg2][rt][ks][lane]
        int lane = g&63, ks = (g>>6)&1, rt = (g>>7)&1, rg2 = (g>>8)&255, node = g>>16;
        int row = rg2*32 + rt*16 + (lane&15);
        int k   = ks*32 + (lane>>4)*8;
        const float* src = st + ((size_t)row*10 + node)*64 + k;
        const float4 v0 = *(const float4*)src;
        const float4 v1 = *(const float4*)(src+4);
        f16x8 h; h[0]=(f16)v0.x; h[1]=(f16)v0.y; h[2]=(f16)v0.z; h[3]=(f16)v0.w;
                 h[4]=(f16)v1.x; h[5]=(f16)v1.y; h[6]=(f16)v1.z; h[7]=(f16)v1.w;
        *(f16x8*)(ws16 + OFF_STF + (size_t)g*8) = h;
    } else if (bid < 3840){                            // action f32 -> f16 compact
        int g = (bid-2560)*256 + t;                    // 327680 float4s
        const float4 v = ((const float4*)ac)[g];
        f16x4 h; h[0]=(f16)v.x; h[1]=(f16)v.y; h[2]=(f16)v.z; h[3]=(f16)v.w;
        *(f16x4*)(ws16 + OFF_AC + (size_t)g*4) = h;
    } else if (bid < 4560){                            // W_edge -> B-fragment order
        int g = (bid-3840)*256 + t;                    // < 184320
        int l = g & 15, q = (g>>4)&3, cg = (g>>6)&7, ks = (g>>9)&3, e = g>>11;
        const float* src = We + e*16384 + (ks*32 + q*8)*128 + cg*16 + l;
        f16x8 h;
        #pragma unroll
        for (int u=0;u<8;u++) h[u] = (f16)src[u*128];
        *(f16x8*)(ws16 + OFF_WEF + (size_t)g*8) = h;
    } else if (bid < 4630){                            // W_node -> B-frags, K-permuted
        int g = (bid-4560)*256 + t;                    // < 17920
        if (g < 17920){
            int l = g&15, q=(g>>4)&3, c=(g>>6)&3, r=g>>8;
            int ks2 = r % 7, kn = r / 7;
            f16x8 h;
            #pragma unroll
            for (int u=0;u<8;u++){
                int knew = ks2*32 + q*8 + u;
                // K-order: [agg 0..127 -> f=knew+80][states/action 128..207 -> f=knew-128][pad]
                int f = (knew < 128) ? (knew + 80) : (knew - 128);
                h[u] = (knew < 208) ? (f16)Wn[kn*13312 + f*64 + c*16 + l] : (f16)0.0f;
            }
            *(f16x8*)(ws16 + OFF_WNF + (size_t)kn*14336 + ((size_t)(ks2*4+c)*64 + q*16 + l)*8) = h;
        }
    } else {                                           // biases * 2log2e, zero pad
        int g = (bid-4630)*256 + t;
        float* be2 = (float*)(ws16 + OFF_BE2);
        if (g < 11520)      be2[g] = S2C*be[g];
        else if (g < 12160) be2[g] = S2C*bn[g-11520];
        else if (g < 12168) ws16[OFF_Z + (g-12160)] = (f16)0.0f;
    }
}

// ---------------- main kernel: 128 rows/block, W via global_load_lds double buffer ----
// 512-thread blocks (8 waves = 4 row-groups x 2 col-halves), 640 blocks, 64 KB LDS.
// Per edge e: load aj+bv (consumed this edge); s_waitcnt vmcnt(8) — edge-e's 4 DMA
// chunks are at depth >=8 (aj:4 + bv:4 issued after them) so this counted wait
// guarantees them WITHOUT draining the in-flight next-edge DMAs; raw s_barrier;
// then issue edge-(e+1) DMA chunks into the other buffer (safe: everyone is past
// the previous edge's compute) and compute edge e. One barrier per edge, zero
// staging VGPRs. At e==8 the DMA slot stages W_node into buf1 for stage 2.
__launch_bounds__(512, 4)
__global__ void gnn_main(const f16* __restrict__ ws16, float* __restrict__ out){
    __shared__ alignas(16) f16 sW0[16384];             // 32 KB: edge W (even), then sAgg
    __shared__ alignas(16) f16 sW1[16384];             // 32 KB: edge W (odd), then W_node

    const f16* stf = ws16 + OFF_STF;
    const f16* Wef = ws16 + OFF_WEF;
    const float* be2 = (const float*)(ws16 + OFF_BE2);
    const float* bn2 = be2 + 11520;

    const int t = threadIdx.x, lane = t&63, wid = t>>6;   // wid 0..7
    const int l15 = lane&15, q = lane>>4, qo = q<<3;
    const int rg = wid>>1, cs = wid&1;                 // row-group 0..3, col-half 0..1

    // bijective XCD-chunk swizzle: 640 = 8 * 80
    const int swz = (blockIdx.x & 7)*80 + (blockIdx.x >> 3);
    const int rb  = swz / 10;                          // 128-row group 0..63
    const int i   = swz - rb*10;                       // node 0..9
    const int e0  = 9*i;
    const int rbrow = rb*4 + rg;                       // this wave's 32-row chunk (0..255)

    // ---- prologue: DMA edge-0 W into sW0 (4 chunks/wave); load ai ----
    {
        const f16* wsrc = Wef + (size_t)e0*16384 + (size_t)(wid*4)*512 + (size_t)lane*8;
        #pragma unroll
        for (int c=0; c<4; ++c)
            GLD16(wsrc + c*512, sW0 + (wid*4 + c)*512);
    }
    __builtin_amdgcn_sched_barrier(0);
    f16x8 ai[4];
    {
        const f16* p = stf + ((size_t)i*256 + rbrow)*2048 + lane*8;
        ai[0] = *(const f16x8*)p;        ai[1] = *(const f16x8*)(p+512);
        ai[2] = *(const f16x8*)(p+1024); ai[3] = *(const f16x8*)(p+1536);
    }

    f32x4 agg[2][4] = {};

    #pragma unroll 1
    for (int e=0; e<9; ++e){
        const int ebase = e0 + e;
        f16* sWc = (e&1) ? sW1 : sW0;                  // compute buffer for edge e
        f16* sWn = (e&1) ? sW0 : sW1;                  // DMA target for edge e+1

        // ---- this edge's A-frags + biases (4+4 vector loads, newest in queue) ----
        const int j = e + (e >= i);
        const f16* pj = stf + ((size_t)j*256 + rbrow)*2048 + lane*8;
        f16x8 aj[4];
        aj[0] = *(const f16x8*)pj;        aj[1] = *(const f16x8*)(pj+512);
        aj[2] = *(const f16x8*)(pj+1024); aj[3] = *(const f16x8*)(pj+1536);
        float bv[4];
        #pragma unroll
        for (int c=0; c<4; ++c) bv[c] = be2[ebase*128 + cs*64 + c*16 + l15];

        // ---- counted wait: edge-e DMA chunks are at depth >= 8 -> done after this ----
        asm volatile("s_waitcnt vmcnt(8)" ::: "memory");
        __builtin_amdgcn_s_barrier();
        __builtin_amdgcn_sched_barrier(0);

        // ---- issue next DMA into the buffer everyone just finished with ----
        if (e < 8){
            const f16* wsrc = Wef + (size_t)(ebase+1)*16384 + (size_t)(wid*4)*512 + (size_t)lane*8;
            #pragma unroll
            for (int c=0; c<4; ++c)
                GLD16(wsrc + c*512, sWn + (wid*4 + c)*512);
        } else {                                       // stage W_node (28 chunks) into sW1
            const f16* wnf = ws16 + OFF_WNF + (size_t)i*14336 + wid*512 + lane*8;
            #pragma unroll
            for (int c2=0; c2<4; ++c2){
                int m = c2*8 + wid;
                if (m < 28) GLD16(wnf + c2*4096, sWn + m*512);
            }
        }
        __builtin_amdgcn_sched_barrier(0);

        // ---- compute edge e from sWc ----
        const f16* wb = sWc + cs*2048 + lane*8;
        #pragma unroll
        for (int rt=0; rt<2; ++rt){
            f32x4 msg[4] = {};
            #pragma unroll
            for (int ks4=0; ks4<4; ++ks4){
                f16x8 a = (ks4 < 2) ? ai[rt*2 + ks4] : aj[rt*2 + (ks4-2)];
                #pragma unroll
                for (int c=0; c<4; ++c){
                    f16x8 b = *(const f16x8*)(wb + (ks4*8 + c)*512);
                    msg[c] = MFMA16(a, b, msg[c]);
                }
            }
            // tanh + aggregate: sum tanh = 9 - 2*sum rcp(exp2(S2C*x+b2)+1)
            #pragma unroll
            for (int c=0; c<4; ++c)
                #pragma unroll
                for (int r2=0; r2<4; ++r2){
                    float tt = __builtin_fmaf(msg[c][r2], S2C, bv[c]);
                    float rr = fast_rcp(fast_exp2(tt) + 1.0f);
                    agg[rt][c][r2] = __builtin_fmaf(-2.0f, rr, agg[rt][c][r2]);
                }
        }
    }

    __syncthreads();   // drain W_node DMAs; all waves done reading sW0 (edge 8's W)

    // ---- agg (C-layout) -> sAgg f16 in sW0 (A-layout, swizzled), +9 fold ----
    #pragma unroll
    for (int rt=0; rt<2; ++rt)
        #pragma unroll
        for (int c=0; c<4; ++c)
            #pragma unroll
            for (int r2=0; r2<4; ++r2){
                int lrow = rg*32 + rt*16 + q*4 + r2;   // 0..127
                int col  = cs*64 + c*16 + l15;         // 0..127
                sW0[lrow*128 + (((col>>3) ^ (lrow&7))<<3) + (col&7)] = (f16)(agg[rt][c][r2] + 9.0f);
            }
    __syncthreads();

    // ---- stage 2: out = tanh([agg|states|action] @ Wn_perm[i] + bn) ; wave = 16 rows ----
    f32x4 acc[4] = {};
    const f16* acp = ws16 + OFF_AC;
    const f16* zb  = ws16 + OFF_Z;
    const int b0 = rb*128;
    #pragma unroll
    for (int ks2=0; ks2<7; ++ks2){
        f16x8 a;
        if (ks2 < 4){                                  // agg region (K 0..127) from LDS
            int lrow = wid*16 + l15;
            a = *(const f16x8*)(sW0 + lrow*128 + (((ks2*4 + q) ^ (l15&7))<<3));
        } else if (ks2 < 6){                           // states region (K 128..191)
            a = *(const f16x8*)(stf + ((size_t)i*256 + rb*4 + (wid>>1))*2048
                                + (wid&1)*1024 + (ks2-4)*512 + lane*8);
        } else {                                       // action (K 192..207) + zero pad
            int row = b0 + wid*16 + l15;
            const f16* ap = (q < 2) ? (acp + ((size_t)row*10 + i)*16 + qo) : zb;
            a = *(const f16x8*)ap;
        }
        #pragma unroll
        for (int c=0; c<4; ++c){
            f16x8 bf = *(const f16x8*)(sW1 + (ks2*4+c)*512 + lane*8);
            acc[c] = MFMA16(a, bf, acc[c]);
        }
    }
    float bnv[4];
    #pragma unroll
    for (int c=0; c<4; ++c) bnv[c] = bn2[i*64 + c*16 + l15];
    #pragma unroll
    for (int c=0; c<4; ++c)
        #pragma unroll
        for (int r2=0; r2<4; ++r2){
            int row = b0 + wid*16 + q*4 + r2;
            int col = c*16 + l15;
            float tt = __builtin_fmaf(acc[c][r2], S2C, bnv[c]);
            float rr = fast_rcp(fast_exp2(tt) + 1.0f);
            out[((size_t)row*10 + i)*64 + col] = __builtin_fmaf(-2.0f, rr, 1.0f);
        }
}

extern "C" void kernel_launch(void* const* d_in, const int* in_sizes, int n_in,
                              void* d_out, int out_size, void* d_ws, size_t ws_size,
                              hipStream_t stream) {
    const float* states = (const float*)d_in[0];
    const float* action = (const float*)d_in[1];
    const float* W_edge = (const float*)d_in[2];
    const float* b_edge = (const float*)d_in[3];
    const float* W_node = (const float*)d_in[4];
    const float* b_node = (const float*)d_in[5];
    f16* ws16 = (f16*)d_ws;   // ~16.4 MB used

    hipLaunchKernelGGL(prep, dim3(4678), dim3(256), 0, stream,
                       states, action, W_edge, b_edge, W_node, b_node, ws16);
    hipLaunchKernelGGL(gnn_main, dim3(640), dim3(512), 0, stream,
                       ws16, (float*)d_out);
}

// Round 5
// 144.288 us; speedup vs baseline: 1.4620x; 1.4620x over previous
//
#include <hip/hip_runtime.h>

typedef _Float16 f16;
typedef _Float16 f16x4 __attribute__((ext_vector_type(4)));
typedef _Float16 f16x8 __attribute__((ext_vector_type(8)));
typedef float    f32x4 __attribute__((ext_vector_type(4)));

#define S2C 2.88539008177792681472f   // 2*log2(e)

// ws layout, f16-element offsets (unchanged — prep is identical to previous rounds)
#define OFF_STF  0u          // states A-frags [10][256 rg2][2 rt][2 ks][64 lane][8]  5242880
#define OFF_AC   5242880u    // action f16 compact [8192][10][16]                     1310720
#define OFF_WEF  6553600u    // W_edge B-frags [90][4 ks][8 cg][64 lane][8]           1474560
#define OFF_WNF  8028160u    // W_node B-frags K-permuted [10][7 ks][4 c][64 lane][8]  143360
#define OFF_BE2  8171520u    // f32: be2[11520], bn2[640]; then 8 f16 zeros
#define OFF_Z    8195840u    // 8 f16 zeros (pad source for action kstep)

__device__ __forceinline__ float fast_exp2(float x){
#if __has_builtin(__builtin_amdgcn_exp2f)
    return __builtin_amdgcn_exp2f(x);
#else
    return exp2f(x);
#endif
}
__device__ __forceinline__ float fast_rcp(float x){
#if __has_builtin(__builtin_amdgcn_rcpf)
    return __builtin_amdgcn_rcpf(x);
#else
    return 1.0f/x;
#endif
}

#define MFMA16(a,b,c) __builtin_amdgcn_mfma_f32_16x16x32_f16(a,b,c,0,0,0)

// direct global->LDS DMA, 16 B/lane; LDS dest is wave-uniform base + lane*16
#define GLD16(g, l) __builtin_amdgcn_global_load_lds( \
    (const __attribute__((address_space(1))) void*)(g), \
    (__attribute__((address_space(3))) void*)(l), 16, 0, 0)

// ---------------- prologue: cvt + fragment-order + bias scale (unchanged) ----------------
__global__ void prep(const float* __restrict__ st, const float* __restrict__ ac,
                     const float* __restrict__ We, const float* __restrict__ be,
                     const float* __restrict__ Wn, const float* __restrict__ bn,
                     f16* __restrict__ ws16){
    const int bid = blockIdx.x, t = threadIdx.x;
    if (bid < 2560){                                   // states -> A-fragment order
        int g = bid*256 + t;                           // [node][rg2][rt][ks][lane]
        int lane = g&63, ks = (g>>6)&1, rt = (g>>7)&1, rg2 = (g>>8)&255, node = g>>16;
        int row = rg2*32 + rt*16 + (lane&15);
        int k   = ks*32 + (lane>>4)*8;
        const float* src = st + ((size_t)row*10 + node)*64 + k;
        const float4 v0 = *(const float4*)src;
        const float4 v1 = *(const float4*)(src+4);
        f16x8 h; h[0]=(f16)v0.x; h[1]=(f16)v0.y; h[2]=(f16)v0.z; h[3]=(f16)v0.w;
                 h[4]=(f16)v1.x; h[5]=(f16)v1.y; h[6]=(f16)v1.z; h[7]=(f16)v1.w;
        *(f16x8*)(ws16 + OFF_STF + (size_t)g*8) = h;
    } else if (bid < 3840){                            // action f32 -> f16 compact
        int g = (bid-2560)*256 + t;                    // 327680 float4s
        const float4 v = ((const float4*)ac)[g];
        f16x4 h; h[0]=(f16)v.x; h[1]=(f16)v.y; h[2]=(f16)v.z; h[3]=(f16)v.w;
        *(f16x4*)(ws16 + OFF_AC + (size_t)g*4) = h;
    } else if (bid < 4560){                            // W_edge -> B-fragment order
        int g = (bid-3840)*256 + t;                    // < 184320
        int l = g & 15, q = (g>>4)&3, cg = (g>>6)&7, ks = (g>>9)&3, e = g>>11;
        const float* src = We + e*16384 + (ks*32 + q*8)*128 + cg*16 + l;
        f16x8 h;
        #pragma unroll
        for (int u=0;u<8;u++) h[u] = (f16)src[u*128];
        *(f16x8*)(ws16 + OFF_WEF + (size_t)g*8) = h;
    } else if (bid < 4630){                            // W_node -> B-frags, K-permuted
        int g = (bid-4560)*256 + t;                    // < 17920
        if (g < 17920){
            int l = g&15, q=(g>>4)&3, c=(g>>6)&3, r=g>>8;
            int ks2 = r % 7, kn = r / 7;
            f16x8 h;
            #pragma unroll
            for (int u=0;u<8;u++){
                int knew = ks2*32 + q*8 + u;
                // K-order: [agg 0..127 -> f=knew+80][states/action 128..207 -> f=knew-128][pad]
                int f = (knew < 128) ? (knew + 80) : (knew - 128);
                h[u] = (knew < 208) ? (f16)Wn[kn*13312 + f*64 + c*16 + l] : (f16)0.0f;
            }
            *(f16x8*)(ws16 + OFF_WNF + (size_t)kn*14336 + ((size_t)(ks2*4+c)*64 + q*16 + l)*8) = h;
        }
    } else {                                           // biases * 2log2e, zero pad
        int g = (bid-4630)*256 + t;
        float* be2 = (float*)(ws16 + OFF_BE2);
        if (g < 11520)      be2[g] = S2C*be[g];
        else if (g < 12160) be2[g] = S2C*bn[g-11520];
        else if (g < 12168) ws16[OFF_Z + (g-12160)] = (f16)0.0f;
    }
}

// ---------------- main kernel: 128 rows/block, W via global_load_lds double buffer ----
// 512-thread blocks (8 waves = 4 row-groups x 2 col-halves), 640 blocks, 64 KB LDS,
// __launch_bounds__(512, 2) -> 128-VGPR budget (CUDA min-blocks semantics), 2 blocks/CU.
//
// SAFE 2-phase pipeline (T3 minimum recipe) — correctness is structural, not
// schedule-dependent (round-4 lesson: hand-counted vmcnt raced under real concurrency):
//   per edge e:  load aj+bv FIRST (so their compiler waits don't in-order-drain the
//   DMAs), THEN issue next-buffer DMA, compute edge e from sWc, then ONE
//   __syncthreads() (full vmcnt/lgkm drain + barrier).  DMA into sWn is issued only
//   after the barrier that ended the iteration which last READ sWn, and is drained
//   by this iteration's barrier before anyone reads it.  At e==8 the DMA slot stages
//   W_node into sW1 for stage 2; sAgg then reuses sW0.
__launch_bounds__(512, 2)
__global__ void gnn_main(const f16* __restrict__ ws16, float* __restrict__ out){
    __shared__ alignas(16) f16 sW0[16384];             // 32 KB: edge W (even), then sAgg
    __shared__ alignas(16) f16 sW1[16384];             // 32 KB: edge W (odd), then W_node

    const f16* stf = ws16 + OFF_STF;
    const f16* Wef = ws16 + OFF_WEF;
    const float* be2 = (const float*)(ws16 + OFF_BE2);
    const float* bn2 = be2 + 11520;

    const int t = threadIdx.x, lane = t&63, wid = t>>6;   // wid 0..7
    const int l15 = lane&15, q = lane>>4, qo = q<<3;
    const int rg = wid>>1, cs = wid&1;                 // row-group 0..3, col-half 0..1

    // bijective XCD-chunk swizzle: 640 = 8 * 80
    const int swz = (blockIdx.x & 7)*80 + (blockIdx.x >> 3);
    const int rb  = swz / 10;                          // 128-row group 0..63
    const int i   = swz - rb*10;                       // node 0..9
    const int e0  = 9*i;
    const int rbrow = rb*4 + rg;                       // this wave's 32-row chunk (0..255)

    // ---- prologue: DMA edge-0 W into sW0 (4 chunks/wave); load ai; full drain ----
    {
        const f16* wsrc = Wef + (size_t)e0*16384 + (size_t)(wid*4)*512 + (size_t)lane*8;
        #pragma unroll
        for (int c=0; c<4; ++c)
            GLD16(wsrc + c*512, sW0 + (wid*4 + c)*512);
    }
    f16x8 ai[4];
    {
        const f16* p = stf + ((size_t)i*256 + rbrow)*2048 + lane*8;
        ai[0] = *(const f16x8*)p;        ai[1] = *(const f16x8*)(p+512);
        ai[2] = *(const f16x8*)(p+1024); ai[3] = *(const f16x8*)(p+1536);
    }
    __syncthreads();                                   // edge-0 W resident in sW0

    f32x4 agg[2][4] = {};

    #pragma unroll 1
    for (int e=0; e<9; ++e){
        const int ebase = e0 + e;
        f16* sWc = (e&1) ? sW1 : sW0;                  // compute buffer for edge e
        f16* sWn = (e&1) ? sW0 : sW1;                  // DMA target (read next iter)

        // ---- this edge's A-frags + biases FIRST (newer DMAs won't be drained by
        //      the compiler's waits for these) ----
        const int j = e + (e >= i);
        const f16* pj = stf + ((size_t)j*256 + rbrow)*2048 + lane*8;
        f16x8 aj[4];
        aj[0] = *(const f16x8*)pj;        aj[1] = *(const f16x8*)(pj+512);
        aj[2] = *(const f16x8*)(pj+1024); aj[3] = *(const f16x8*)(pj+1536);
        float bv[4];
        #pragma unroll
        for (int c=0; c<4; ++c) bv[c] = be2[ebase*128 + cs*64 + c*16 + l15];

        // ---- issue next-buffer DMA; drains at this iteration's trailing barrier ----
        if (e < 8){
            const f16* wsrc = Wef + (size_t)(ebase+1)*16384 + (size_t)(wid*4)*512 + (size_t)lane*8;
            #pragma unroll
            for (int c=0; c<4; ++c)
                GLD16(wsrc + c*512, sWn + (wid*4 + c)*512);
        } else {                                       // stage W_node (28 chunks) into sW1
            const f16* wnf = ws16 + OFF_WNF + (size_t)i*14336 + wid*512 + lane*8;
            #pragma unroll
            for (int c2=0; c2<4; ++c2){
                int m = c2*8 + wid;
                if (m < 28) GLD16(wnf + c2*4096, sWn + m*512);
            }
        }

        // ---- compute edge e from sWc ----
        const f16* wb = sWc + cs*2048 + lane*8;
        #pragma unroll
        for (int rt=0; rt<2; ++rt){
            f32x4 msg[4] = {};
            #pragma unroll
            for (int ks4=0; ks4<4; ++ks4){
                f16x8 a = (ks4 < 2) ? ai[rt*2 + ks4] : aj[rt*2 + (ks4-2)];
                #pragma unroll
                for (int c=0; c<4; ++c){
                    f16x8 b = *(const f16x8*)(wb + (ks4*8 + c)*512);
                    msg[c] = MFMA16(a, b, msg[c]);
                }
            }
            // tanh + aggregate: sum tanh = 9 - 2*sum rcp(exp2(S2C*x+b2)+1)
            #pragma unroll
            for (int c=0; c<4; ++c)
                #pragma unroll
                for (int r2=0; r2<4; ++r2){
                    float tt = __builtin_fmaf(msg[c][r2], S2C, bv[c]);
                    float rr = fast_rcp(fast_exp2(tt) + 1.0f);
                    agg[rt][c][r2] = __builtin_fmaf(-2.0f, rr, agg[rt][c][r2]);
                }
        }

        // ---- full drain + barrier: DMA writes visible, sWc reads done everywhere ----
        __syncthreads();
    }

    // sW0 free (edge 8 read it, barrier passed); sW1 holds W_node (drained above)

    // ---- agg (C-layout) -> sAgg f16 in sW0 (A-layout, swizzled), +9 fold ----
    #pragma unroll
    for (int rt=0; rt<2; ++rt)
        #pragma unroll
        for (int c=0; c<4; ++c)
            #pragma unroll
            for (int r2=0; r2<4; ++r2){
                int lrow = rg*32 + rt*16 + q*4 + r2;   // 0..127
                int col  = cs*64 + c*16 + l15;         // 0..127
                sW0[lrow*128 + (((col>>3) ^ (lrow&7))<<3) + (col&7)] = (f16)(agg[rt][c][r2] + 9.0f);
            }
    __syncthreads();

    // ---- stage 2: out = tanh([agg|states|action] @ Wn_perm[i] + bn) ; wave = 16 rows ----
    f32x4 acc[4] = {};
    const f16* acp = ws16 + OFF_AC;
    const f16* zb  = ws16 + OFF_Z;
    const int b0 = rb*128;
    #pragma unroll
    for (int ks2=0; ks2<7; ++ks2){
        f16x8 a;
        if (ks2 < 4){                                  // agg region (K 0..127) from LDS
            int lrow = wid*16 + l15;
            a = *(const f16x8*)(sW0 + lrow*128 + (((ks2*4 + q) ^ (l15&7))<<3));
        } else if (ks2 < 6){                           // states region (K 128..191)
            a = *(const f16x8*)(stf + ((size_t)i*256 + rb*4 + (wid>>1))*2048
                                + (wid&1)*1024 + (ks2-4)*512 + lane*8);
        } else {                                       // action (K 192..207) + zero pad
            int row = b0 + wid*16 + l15;
            const f16* ap = (q < 2) ? (acp + ((size_t)row*10 + i)*16 + qo) : zb;
            a = *(const f16x8*)ap;
        }
        #pragma unroll
        for (int c=0; c<4; ++c){
            f16x8 bf = *(const f16x8*)(sW1 + (ks2*4+c)*512 + lane*8);
            acc[c] = MFMA16(a, bf, acc[c]);
        }
    }
    float bnv[4];
    #pragma unroll
    for (int c=0; c<4; ++c) bnv[c] = bn2[i*64 + c*16 + l15];
    #pragma unroll
    for (int c=0; c<4; ++c)
        #pragma unroll
        for (int r2=0; r2<4; ++r2){
            int row = b0 + wid*16 + q*4 + r2;
            int col = c*16 + l15;
            float tt = __builtin_fmaf(acc[c][r2], S2C, bnv[c]);
            float rr = fast_rcp(fast_exp2(tt) + 1.0f);
            out[((size_t)row*10 + i)*64 + col] = __builtin_fmaf(-2.0f, rr, 1.0f);
        }
}

extern "C" void kernel_launch(void* const* d_in, const int* in_sizes, int n_in,
                              void* d_out, int out_size, void* d_ws, size_t ws_size,
                              hipStream_t stream) {
    const float* states = (const float*)d_in[0];
    const float* action = (const float*)d_in[1];
    const float* W_edge = (const float*)d_in[2];
    const float* b_edge = (const float*)d_in[3];
    const float* W_node = (const float*)d_in[4];
    const float* b_node = (const float*)d_in[5];
    f16* ws16 = (f16*)d_ws;   // ~16.4 MB used

    hipLaunchKernelGGL(prep, dim3(4678), dim3(256), 0, stream,
                       states, action, W_edge, b_edge, W_node, b_node, ws16);
    hipLaunchKernelGGL(gnn_main, dim3(640), dim3(512), 0, stream,
                       ws16, (float*)d_out);
}